// Round 1
// baseline (1417.444 us; speedup 1.0000x reference)
//
#include <hip/hip_runtime.h>

#define NN 50000
#define NE 800000

// ws layout (float offsets)
static const size_t XOFF   = 0;          // x        [50000*64]
static const size_t POFF   = 3200000;    // P        [50000*128]
static const size_t QOFF   = 9600000;    // Q        [50000*128]
static const size_t N1OFF  = 16000000;   // nfoc1    [50000*64]  (float)
static const size_t N2OFF  = 19200000;   // nfoc2enc [50000*64]  (uint)
static const size_t DEGOFF = 22400000;   // deg      [50000]
static const size_t W2FOFF = 22450000;   // w2f      [128*128]
static const size_t W2GOFF = 22466384;   // w2gate   [128]

__device__ __forceinline__ unsigned fenc(float f){
  unsigned b = __float_as_uint(f);
  return (b & 0x80000000u) ? ~b : (b | 0x80000000u);
}
__device__ __forceinline__ float fdec(unsigned u){
  return (u & 0x80000000u) ? __uint_as_float(u & 0x7fffffffu) : __uint_as_float(~u);
}
__device__ __forceinline__ float lrelu(float v){ return v > 0.f ? v : 0.2f * v; }

// 64x64 tile GEMM: acc[4][4] = bias + sIn(64x64, pad65) @ W(64x64 row-major)
__device__ __forceinline__ void gemm64(const float (*sIn)[65], const float* __restrict__ W,
                                       const float* __restrict__ bias, int t, float acc[4][4])
{
  const int c0 = (t & 15) * 4, r0 = (t >> 4) * 4;
  const float4 b4 = *(const float4*)&bias[c0];
  #pragma unroll
  for (int j = 0; j < 4; ++j){ acc[j][0]=b4.x; acc[j][1]=b4.y; acc[j][2]=b4.z; acc[j][3]=b4.w; }
  #pragma unroll 4
  for (int k = 0; k < 64; ++k){
    const float4 w4 = *(const float4*)&W[k*64 + c0];
    #pragma unroll
    for (int j = 0; j < 4; ++j){
      const float a = sIn[r0+j][k];
      acc[j][0] = fmaf(a, w4.x, acc[j][0]);
      acc[j][1] = fmaf(a, w4.y, acc[j][1]);
      acc[j][2] = fmaf(a, w4.z, acc[j][2]);
      acc[j][3] = fmaf(a, w4.w, acc[j][3]);
    }
  }
}

// Re-layout msg_w2 [128][129] -> w2f [128][128] (cols 1..128) + w2gate[128] (col 0)
__global__ __launch_bounds__(256) void relayout_w2(const float* __restrict__ w2,
                                                   float* __restrict__ w2f,
                                                   float* __restrict__ w2g)
{
  int i = blockIdx.x * 256 + threadIdx.x;
  if (i < 16384){
    int k = i >> 7, c = i & 127;
    w2f[i] = w2[k*129 + 1 + c];
  } else if (i < 16512){
    int k = i - 16384;
    w2g[k] = w2[k*129];
  }
}

// Node-side precompute: x = residual(nf); x1 = x@l1w+b -> out; P = x@W1_top; Q = x@W1_bot.
// Also zero-init nfoc1 / nfoc2enc / deg for this node range.
__global__ __launch_bounds__(256) void node_pre(
    const float* __restrict__ nf,
    const float* __restrict__ rw1, const float* __restrict__ rb1,
    const float* __restrict__ rw2, const float* __restrict__ rb2,
    const float* __restrict__ l1w, const float* __restrict__ l1b,
    const float* __restrict__ w1,   // msg_w1 [128][128]
    float* __restrict__ x_out, float* __restrict__ Pp, float* __restrict__ Qp,
    float* __restrict__ out,
    float* __restrict__ nfoc1, unsigned* __restrict__ nfoc2, float* __restrict__ deg)
{
  __shared__ float sA[64][65];
  __shared__ float sB[64][65];
  const int t = threadIdx.x;
  const int n0 = blockIdx.x * 64;
  const int rr = t >> 4, c4 = (t & 15) * 4;

  // load nf tile (coalesced: 16 lanes cover one 256B row)
  #pragma unroll
  for (int i = 0; i < 4; ++i){
    int r = rr + i*16, n = n0 + r;
    float4 v = make_float4(0.f,0.f,0.f,0.f);
    if (n < NN) v = *(const float4*)&nf[n*64 + c4];
    sA[r][c4+0]=v.x; sA[r][c4+1]=v.y; sA[r][c4+2]=v.z; sA[r][c4+3]=v.w;
  }
  __syncthreads();

  float acc[4][4];
  const int c0 = (t & 15) * 4, r0 = (t >> 4) * 4;

  // tmp = nf@rw1 + rb1 -> sB
  gemm64(sA, rw1, rb1, t, acc);
  #pragma unroll
  for (int j = 0; j < 4; ++j)
    #pragma unroll
    for (int i = 0; i < 4; ++i) sB[r0+j][c0+i] = acc[j][i];
  __syncthreads();

  // x = tmp@rw2 + rb2 + nf -> sA (own elements) + global
  gemm64(sB, rw2, rb2, t, acc);
  #pragma unroll
  for (int j = 0; j < 4; ++j)
    #pragma unroll
    for (int i = 0; i < 4; ++i) acc[j][i] += sA[r0+j][c0+i];
  #pragma unroll
  for (int j = 0; j < 4; ++j){
    #pragma unroll
    for (int i = 0; i < 4; ++i) sA[r0+j][c0+i] = acc[j][i];
    int n = n0 + r0 + j;
    if (n < NN){
      float4 v = make_float4(acc[j][0],acc[j][1],acc[j][2],acc[j][3]);
      *(float4*)&x_out[n*64 + c0] = v;
    }
  }
  __syncthreads();

  // x1 = x@l1w + l1b -> out (d_out)
  gemm64(sA, l1w, l1b, t, acc);
  #pragma unroll
  for (int j = 0; j < 4; ++j){
    int n = n0 + r0 + j;
    if (n < NN){
      float4 v = make_float4(acc[j][0],acc[j][1],acc[j][2],acc[j][3]);
      *(float4*)&out[n*64 + c0] = v;
    }
  }

  // P = x@W1[0:64,:], Q = x@W1[64:128,:]  (no bias; b1 added per-edge)
  #pragma unroll
  for (int part = 0; part < 2; ++part){
    float* dstp = part ? Qp : Pp;
    const float* Wp = w1 + (size_t)part * 64 * 128;
    for (int ch = 0; ch < 2; ++ch){
      float a2[4][4];
      #pragma unroll
      for (int j = 0; j < 4; ++j)
        #pragma unroll
        for (int i = 0; i < 4; ++i) a2[j][i] = 0.f;
      #pragma unroll 4
      for (int k = 0; k < 64; ++k){
        const float4 w4 = *(const float4*)&Wp[k*128 + ch*64 + c0];
        #pragma unroll
        for (int j = 0; j < 4; ++j){
          const float a = sA[r0+j][k];
          a2[j][0] = fmaf(a, w4.x, a2[j][0]);
          a2[j][1] = fmaf(a, w4.y, a2[j][1]);
          a2[j][2] = fmaf(a, w4.z, a2[j][2]);
          a2[j][3] = fmaf(a, w4.w, a2[j][3]);
        }
      }
      #pragma unroll
      for (int j = 0; j < 4; ++j){
        int n = n0 + r0 + j;
        if (n < NN){
          float4 v = make_float4(a2[j][0],a2[j][1],a2[j][2],a2[j][3]);
          *(float4*)&dstp[n*128 + ch*64 + c0] = v;
        }
      }
    }
  }

  // zero-init scatter targets for this node tile
  #pragma unroll
  for (int i = 0; i < 16; ++i){
    int idx = t + 256*i;                 // 0..4095
    size_t flat = (size_t)n0*64 + idx;
    if (flat < (size_t)NN*64){ nfoc1[flat] = 0.f; nfoc2[flat] = 0u; }
  }
  if (t < 64){
    int n = n0 + t;
    if (n < NN) deg[n] = 0.f;
  }
}

// Edge MLP + scatter. 64 edges per block.
__global__ __launch_bounds__(256) void edge_mlp(
    const int* __restrict__ src, const int* __restrict__ dst,
    const float* __restrict__ Pp, const float* __restrict__ Qp,
    const float* __restrict__ b1,   // msg_b1 [128]
    const float* __restrict__ w2f, const float* __restrict__ w2g,
    const float* __restrict__ b2,   // msg_b2 [129]
    float* __restrict__ nfoc1, unsigned* __restrict__ nfoc2, float* __restrict__ deg)
{
  __shared__ float sM[64][132];
  __shared__ float sK[64];
  __shared__ int   sD[64];
  __shared__ float sPart[64][5];
  const int t = threadIdx.x;
  const int e0 = blockIdx.x * 64;

  // phase 1: gather P[src]+Q[dst]+b1, leaky-relu -> sM
  {
    const int el = t >> 2, q = t & 3;
    const int e = e0 + el;
    const int s = src[e], d = dst[e];
    if (q == 0) sD[el] = d;
    #pragma unroll
    for (int i = 0; i < 8; ++i){
      const int c = q*4 + i*16;
      const float4 p  = *(const float4*)&Pp[(size_t)s*128 + c];
      const float4 qq = *(const float4*)&Qp[(size_t)d*128 + c];
      const float4 bb = *(const float4*)&b1[c];
      sM[el][c+0] = lrelu(p.x + qq.x + bb.x);
      sM[el][c+1] = lrelu(p.y + qq.y + bb.y);
      sM[el][c+2] = lrelu(p.z + qq.z + bb.z);
      sM[el][c+3] = lrelu(p.w + qq.w + bb.w);
    }
  }
  __syncthreads();

  // phase 2: gate column partials
  {
    const int r = t & 63, part = t >> 6;
    float a = 0.f;
    #pragma unroll 4
    for (int kk = 0; kk < 32; ++kk){
      int k = part*32 + kk;
      a = fmaf(sM[r][k], w2g[k], a);
    }
    sPart[r][part] = a;
  }
  __syncthreads();
  if (t < 64){
    float g = sPart[t][0] + sPart[t][1] + sPart[t][2] + sPart[t][3] + b2[0];
    sK[t] = 1.f / (1.f + expf(-g));
    unsafeAtomicAdd(&deg[sD[t]], 1.0f);
  }
  __syncthreads();

  // phase 3: o[:,1:129] = sM(64x128) @ w2f(128x128)
  const int cg = t & 31, rg = t >> 5;
  const int c0 = cg * 4, r0 = rg * 8;
  float acc[8][4];
  #pragma unroll
  for (int j = 0; j < 8; ++j)
    #pragma unroll
    for (int i = 0; i < 4; ++i) acc[j][i] = 0.f;

  for (int k = 0; k < 128; k += 4){
    const float4 w0 = *(const float4*)&w2f[(k+0)*128 + c0];
    const float4 w1_ = *(const float4*)&w2f[(k+1)*128 + c0];
    const float4 w2_ = *(const float4*)&w2f[(k+2)*128 + c0];
    const float4 w3_ = *(const float4*)&w2f[(k+3)*128 + c0];
    #pragma unroll
    for (int j = 0; j < 8; ++j){
      const float4 a = *(const float4*)&sM[r0+j][k];
      acc[j][0] = fmaf(a.x,w0.x, fmaf(a.y,w1_.x, fmaf(a.z,w2_.x, fmaf(a.w,w3_.x, acc[j][0]))));
      acc[j][1] = fmaf(a.x,w0.y, fmaf(a.y,w1_.y, fmaf(a.z,w2_.y, fmaf(a.w,w3_.y, acc[j][1]))));
      acc[j][2] = fmaf(a.x,w0.z, fmaf(a.y,w1_.z, fmaf(a.z,w2_.z, fmaf(a.w,w3_.z, acc[j][2]))));
      acc[j][3] = fmaf(a.x,w0.w, fmaf(a.y,w1_.w, fmaf(a.z,w2_.w, fmaf(a.w,w3_.w, acc[j][3]))));
    }
  }

  // epilogue: bias, gate, scatter
  float bb[4];
  #pragma unroll
  for (int i = 0; i < 4; ++i) bb[i] = b2[1 + c0 + i];
  #pragma unroll
  for (int j = 0; j < 8; ++j){
    const int r = r0 + j;
    const float kk = sK[r];
    const int d = sD[r];
    if (c0 < 64){
      #pragma unroll
      for (int i = 0; i < 4; ++i){
        float v = (acc[j][i] + bb[i]) * kk;
        unsafeAtomicAdd(&nfoc1[(size_t)d*64 + c0 + i], v);
      }
    } else {
      #pragma unroll
      for (int i = 0; i < 4; ++i){
        float v = (acc[j][i] + bb[i]) * kk;
        atomicMax(&nfoc2[(size_t)d*64 + (c0-64) + i], fenc(v));
      }
    }
  }
}

// Node-side post: new_x = concat(x,nfoc1,nfoc2)@red_w+red_b; out += new_x@l2w+l2b
__global__ __launch_bounds__(256) void node_post(
    const float* __restrict__ x, const float* __restrict__ nfoc1,
    const unsigned* __restrict__ nfoc2, const float* __restrict__ deg,
    const float* __restrict__ redw, const float* __restrict__ redb,
    const float* __restrict__ l2w, const float* __restrict__ l2b,
    float* __restrict__ out)
{
  __shared__ float sC[64][197];
  __shared__ float sN[64][65];
  const int t = threadIdx.x;
  const int n0 = blockIdx.x * 64;
  const int rr = t >> 4, c4 = (t & 15) * 4;

  // stage concat tile
  #pragma unroll
  for (int i = 0; i < 4; ++i){
    int r = rr + i*16, n = n0 + r;
    float4 xv = make_float4(0,0,0,0), f1 = make_float4(0,0,0,0);
    uint4 f2 = make_uint4(0,0,0,0);
    float dg = 0.f;
    if (n < NN){
      xv = *(const float4*)&x[(size_t)n*64 + c4];
      f1 = *(const float4*)&nfoc1[(size_t)n*64 + c4];
      f2 = *(const uint4*)&nfoc2[(size_t)n*64 + c4];
      dg = deg[n];
    }
    sC[r][c4+0]=xv.x; sC[r][c4+1]=xv.y; sC[r][c4+2]=xv.z; sC[r][c4+3]=xv.w;
    sC[r][64+c4+0]=f1.x; sC[r][64+c4+1]=f1.y; sC[r][64+c4+2]=f1.z; sC[r][64+c4+3]=f1.w;
    bool has = dg > 0.f;
    sC[r][128+c4+0] = has ? fdec(f2.x) : 0.f;
    sC[r][128+c4+1] = has ? fdec(f2.y) : 0.f;
    sC[r][128+c4+2] = has ? fdec(f2.z) : 0.f;
    sC[r][128+c4+3] = has ? fdec(f2.w) : 0.f;
  }
  __syncthreads();

  const int c0 = (t & 15) * 4, r0 = (t >> 4) * 4;
  float acc[4][4];

  // new_x = sC @ redw + redb
  {
    const float4 b4 = *(const float4*)&redb[c0];
    #pragma unroll
    for (int j = 0; j < 4; ++j){ acc[j][0]=b4.x; acc[j][1]=b4.y; acc[j][2]=b4.z; acc[j][3]=b4.w; }
    #pragma unroll 4
    for (int k = 0; k < 192; ++k){
      const float4 w4 = *(const float4*)&redw[k*64 + c0];
      #pragma unroll
      for (int j = 0; j < 4; ++j){
        const float a = sC[r0+j][k];
        acc[j][0] = fmaf(a, w4.x, acc[j][0]);
        acc[j][1] = fmaf(a, w4.y, acc[j][1]);
        acc[j][2] = fmaf(a, w4.z, acc[j][2]);
        acc[j][3] = fmaf(a, w4.w, acc[j][3]);
      }
    }
    #pragma unroll
    for (int j = 0; j < 4; ++j)
      #pragma unroll
      for (int i = 0; i < 4; ++i) sN[r0+j][c0+i] = acc[j][i];
  }
  __syncthreads();

  // x2 = sN @ l2w + l2b; out += x2
  gemm64(sN, l2w, l2b, t, acc);
  #pragma unroll
  for (int j = 0; j < 4; ++j){
    int n = n0 + r0 + j;
    if (n < NN){
      float4 cur = *(const float4*)&out[(size_t)n*64 + c0];
      cur.x += acc[j][0]; cur.y += acc[j][1]; cur.z += acc[j][2]; cur.w += acc[j][3];
      *(float4*)&out[(size_t)n*64 + c0] = cur;
    }
  }
}

extern "C" void kernel_launch(void* const* d_in, const int* in_sizes, int n_in,
                              void* d_out, int out_size, void* d_ws, size_t ws_size,
                              hipStream_t stream)
{
  const float* nf   = (const float*)d_in[0];
  const int*   src  = (const int*)d_in[1];
  const int*   dst  = (const int*)d_in[2];
  const float* rw1  = (const float*)d_in[3];
  const float* rb1  = (const float*)d_in[4];
  const float* rw2  = (const float*)d_in[5];
  const float* rb2  = (const float*)d_in[6];
  const float* l1w  = (const float*)d_in[7];
  const float* l1b  = (const float*)d_in[8];
  const float* l2w  = (const float*)d_in[9];
  const float* l2b  = (const float*)d_in[10];
  const float* mw1  = (const float*)d_in[11];
  const float* mb1  = (const float*)d_in[12];
  const float* mw2  = (const float*)d_in[13];
  const float* mb2  = (const float*)d_in[14];
  const float* redw = (const float*)d_in[15];
  const float* redb = (const float*)d_in[16];

  float* ws = (float*)d_ws;
  float* x     = ws + XOFF;
  float* P     = ws + POFF;
  float* Q     = ws + QOFF;
  float* nfoc1 = ws + N1OFF;
  unsigned* nfoc2 = (unsigned*)(ws + N2OFF);
  float* deg   = ws + DEGOFF;
  float* w2f   = ws + W2FOFF;
  float* w2g   = ws + W2GOFF;
  float* out   = (float*)d_out;

  hipLaunchKernelGGL(relayout_w2, dim3(65), dim3(256), 0, stream, mw2, w2f, w2g);
  hipLaunchKernelGGL(node_pre, dim3(782), dim3(256), 0, stream,
                     nf, rw1, rb1, rw2, rb2, l1w, l1b, mw1,
                     x, P, Q, out, nfoc1, nfoc2, deg);
  hipLaunchKernelGGL(edge_mlp, dim3(12500), dim3(256), 0, stream,
                     src, dst, P, Q, mb1, w2f, w2g, mb2, nfoc1, nfoc2, deg);
  hipLaunchKernelGGL(node_post, dim3(782), dim3(256), 0, stream,
                     x, nfoc1, nfoc2, deg, redw, redb, l2w, l2b, out);
}

// Round 2
// 780.799 us; speedup vs baseline: 1.8154x; 1.8154x over previous
//
#include <hip/hip_runtime.h>

#define NN 50000
#define NE 800000

typedef _Float16 half8 __attribute__((ext_vector_type(8)));
typedef _Float16 half4 __attribute__((ext_vector_type(4)));

// ws layout (float offsets)
static const size_t XOFF   = 0;          // x        [50000*64]
static const size_t POFF   = 3200000;    // P        [50000*128]
static const size_t QOFF   = 9600000;    // Q        [50000*128]
static const size_t N1OFF  = 16000000;   // nfoc1    [50000*64]  (float)
static const size_t N2OFF  = 19200000;   // nfoc2    [50000*64]  (float)
static const size_t W2FOFF = 22400000;   // w2f      [128*128]
static const size_t W2GOFF = 22416384;   // w2gate   [128]
static const size_t CNTOFF = 22416512;   // counts   [50000] (u32)
static const size_t STOFF  = 22466512;   // starts   [50001] (u32)
static const size_t CUROFF = 22516520;   // cursor   [50000] (u32)
static const size_t PERMOFF= 22566520;   // perm     [800000] (u32)
static const size_t EBUFOFF= 23366528;   // ebuf     [chunk*128] (_Float16), 16B-aligned

__device__ __forceinline__ float lrelu(float v){ return v > 0.f ? v : 0.2f * v; }

// 64x64 tile GEMM: acc[4][4] = bias + sIn(64x64, pad65) @ W(64x64 row-major)
__device__ __forceinline__ void gemm64(const float (*sIn)[65], const float* __restrict__ W,
                                       const float* __restrict__ bias, int t, float acc[4][4])
{
  const int c0 = (t & 15) * 4, r0 = (t >> 4) * 4;
  const float4 b4 = *(const float4*)&bias[c0];
  #pragma unroll
  for (int j = 0; j < 4; ++j){ acc[j][0]=b4.x; acc[j][1]=b4.y; acc[j][2]=b4.z; acc[j][3]=b4.w; }
  #pragma unroll 4
  for (int k = 0; k < 64; ++k){
    const float4 w4 = *(const float4*)&W[k*64 + c0];
    #pragma unroll
    for (int j = 0; j < 4; ++j){
      const float a = sIn[r0+j][k];
      acc[j][0] = fmaf(a, w4.x, acc[j][0]);
      acc[j][1] = fmaf(a, w4.y, acc[j][1]);
      acc[j][2] = fmaf(a, w4.z, acc[j][2]);
      acc[j][3] = fmaf(a, w4.w, acc[j][3]);
    }
  }
}

// Re-layout msg_w2 [128][129] -> w2f[128][128] + w2gate[128]; zero counts.
__global__ __launch_bounds__(256) void relayout_w2(const float* __restrict__ w2,
                                                   float* __restrict__ w2f,
                                                   float* __restrict__ w2g,
                                                   unsigned* __restrict__ counts)
{
  int i = blockIdx.x * 256 + threadIdx.x;
  if (i < 16384){
    int k = i >> 7, c = i & 127;
    w2f[i] = w2[k*129 + 1 + c];
  } else if (i < 16512){
    int k = i - 16384;
    w2g[k] = w2[k*129];
  } else if (i < 16512 + NN){
    counts[i - 16512] = 0u;
  }
}

// histogram of dst
__global__ __launch_bounds__(256) void hist_k(const int* __restrict__ dst,
                                              unsigned* __restrict__ counts)
{
  int e = blockIdx.x * 256 + threadIdx.x;
  if (e < NE) atomicAdd(&counts[dst[e]], 1u);
}

// single-block exclusive scan of counts -> starts[0..NN], cursor copy
__global__ __launch_bounds__(1024) void scan_k(const unsigned* __restrict__ counts,
                                               unsigned* __restrict__ starts,
                                               unsigned* __restrict__ cursor)
{
  __shared__ unsigned sc[1024];
  const int i = threadIdx.x;
  const int L = 49;               // 1024*49 = 50176 >= 50000
  const int base = i * L;
  unsigned s = 0;
  for (int j = 0; j < L; ++j){
    int n = base + j;
    if (n < NN) s += counts[n];
  }
  sc[i] = s; __syncthreads();
  for (int d = 1; d < 1024; d <<= 1){
    unsigned v = 0;
    if (i >= d) v = sc[i - d];
    __syncthreads();
    sc[i] += v;
    __syncthreads();
  }
  unsigned run = sc[i] - s;       // exclusive offset
  for (int j = 0; j < L; ++j){
    int n = base + j;
    if (n < NN){
      starts[n] = run; cursor[n] = run;
      run += counts[n];
    }
  }
  if (i == 1023) starts[NN] = sc[1023];
}

// slot assignment: perm[slot] = edge id, slots grouped by dst
__global__ __launch_bounds__(256) void assign_k(const int* __restrict__ dst,
                                                unsigned* __restrict__ cursor,
                                                unsigned* __restrict__ perm)
{
  int e = blockIdx.x * 256 + threadIdx.x;
  if (e < NE){
    unsigned slot = atomicAdd(&cursor[dst[e]], 1u);
    perm[slot] = (unsigned)e;
  }
}

// Node-side precompute: x = residual(nf); x1 = x@l1w+b -> out; P = x@W1_top; Q = x@W1_bot.
__global__ __launch_bounds__(256) void node_pre(
    const float* __restrict__ nf,
    const float* __restrict__ rw1, const float* __restrict__ rb1,
    const float* __restrict__ rw2, const float* __restrict__ rb2,
    const float* __restrict__ l1w, const float* __restrict__ l1b,
    const float* __restrict__ w1,   // msg_w1 [128][128]
    float* __restrict__ x_out, float* __restrict__ Pp, float* __restrict__ Qp,
    float* __restrict__ out)
{
  __shared__ float sA[64][65];
  __shared__ float sB[64][65];
  const int t = threadIdx.x;
  const int n0 = blockIdx.x * 64;
  const int rr = t >> 4, c4 = (t & 15) * 4;

  #pragma unroll
  for (int i = 0; i < 4; ++i){
    int r = rr + i*16, n = n0 + r;
    float4 v = make_float4(0.f,0.f,0.f,0.f);
    if (n < NN) v = *(const float4*)&nf[n*64 + c4];
    sA[r][c4+0]=v.x; sA[r][c4+1]=v.y; sA[r][c4+2]=v.z; sA[r][c4+3]=v.w;
  }
  __syncthreads();

  float acc[4][4];
  const int c0 = (t & 15) * 4, r0 = (t >> 4) * 4;

  gemm64(sA, rw1, rb1, t, acc);
  #pragma unroll
  for (int j = 0; j < 4; ++j)
    #pragma unroll
    for (int i = 0; i < 4; ++i) sB[r0+j][c0+i] = acc[j][i];
  __syncthreads();

  gemm64(sB, rw2, rb2, t, acc);
  #pragma unroll
  for (int j = 0; j < 4; ++j)
    #pragma unroll
    for (int i = 0; i < 4; ++i) acc[j][i] += sA[r0+j][c0+i];
  #pragma unroll
  for (int j = 0; j < 4; ++j){
    #pragma unroll
    for (int i = 0; i < 4; ++i) sA[r0+j][c0+i] = acc[j][i];
    int n = n0 + r0 + j;
    if (n < NN){
      float4 v = make_float4(acc[j][0],acc[j][1],acc[j][2],acc[j][3]);
      *(float4*)&x_out[n*64 + c0] = v;
    }
  }
  __syncthreads();

  gemm64(sA, l1w, l1b, t, acc);
  #pragma unroll
  for (int j = 0; j < 4; ++j){
    int n = n0 + r0 + j;
    if (n < NN){
      float4 v = make_float4(acc[j][0],acc[j][1],acc[j][2],acc[j][3]);
      *(float4*)&out[n*64 + c0] = v;
    }
  }

  #pragma unroll
  for (int part = 0; part < 2; ++part){
    float* dstp = part ? Qp : Pp;
    const float* Wp = w1 + (size_t)part * 64 * 128;
    for (int ch = 0; ch < 2; ++ch){
      float a2[4][4];
      #pragma unroll
      for (int j = 0; j < 4; ++j)
        #pragma unroll
        for (int i = 0; i < 4; ++i) a2[j][i] = 0.f;
      #pragma unroll 4
      for (int k = 0; k < 64; ++k){
        const float4 w4 = *(const float4*)&Wp[k*128 + ch*64 + c0];
        #pragma unroll
        for (int j = 0; j < 4; ++j){
          const float a = sA[r0+j][k];
          a2[j][0] = fmaf(a, w4.x, a2[j][0]);
          a2[j][1] = fmaf(a, w4.y, a2[j][1]);
          a2[j][2] = fmaf(a, w4.z, a2[j][2]);
          a2[j][3] = fmaf(a, w4.w, a2[j][3]);
        }
      }
      #pragma unroll
      for (int j = 0; j < 4; ++j){
        int n = n0 + r0 + j;
        if (n < NN){
          float4 v = make_float4(a2[j][0],a2[j][1],a2[j][2],a2[j][3]);
          *(float4*)&dstp[n*128 + ch*64 + c0] = v;
        }
      }
    }
  }
}

// Edge MLP over sorted slots; writes gated f1|f2 as f16 row [rel_slot][128]. No atomics.
__global__ __launch_bounds__(256) void edge_mlp2(
    const int* __restrict__ src, const int* __restrict__ dst,
    const float* __restrict__ Pp, const float* __restrict__ Qp,
    const float* __restrict__ b1,
    const float* __restrict__ w2f, const float* __restrict__ w2g,
    const float* __restrict__ b2,
    const unsigned* __restrict__ perm,   // pre-offset to chunk base
    _Float16* __restrict__ ebuf)
{
  __shared__ float sM[64][132];
  __shared__ float sK[64];
  __shared__ float sPart[64][5];
  const int t = threadIdx.x;
  const int sl0 = blockIdx.x * 64;     // rel slot base within chunk

  // phase 1: gather P[src]+Q[dst]+b1, leaky-relu -> sM
  {
    const int el = t >> 2, q = t & 3;
    const unsigned e = perm[sl0 + el];
    const int s = src[e], d = dst[e];
    #pragma unroll
    for (int i = 0; i < 8; ++i){
      const int c = q*4 + i*16;
      const float4 p  = *(const float4*)&Pp[(size_t)s*128 + c];
      const float4 qq = *(const float4*)&Qp[(size_t)d*128 + c];
      const float4 bb = *(const float4*)&b1[c];
      sM[el][c+0] = lrelu(p.x + qq.x + bb.x);
      sM[el][c+1] = lrelu(p.y + qq.y + bb.y);
      sM[el][c+2] = lrelu(p.z + qq.z + bb.z);
      sM[el][c+3] = lrelu(p.w + qq.w + bb.w);
    }
  }
  __syncthreads();

  // phase 2: gate column partials
  {
    const int r = t & 63, part = t >> 6;
    float a = 0.f;
    #pragma unroll 4
    for (int kk = 0; kk < 32; ++kk){
      int k = part*32 + kk;
      a = fmaf(sM[r][k], w2g[k], a);
    }
    sPart[r][part] = a;
  }
  __syncthreads();
  if (t < 64){
    float g = sPart[t][0] + sPart[t][1] + sPart[t][2] + sPart[t][3] + b2[0];
    sK[t] = 1.f / (1.f + expf(-g));
  }
  __syncthreads();

  // phase 3: o[:,1:129] = sM(64x128) @ w2f(128x128)
  const int cg = t & 31, rg = t >> 5;
  const int c0 = cg * 4, r0 = rg * 8;
  float acc[8][4];
  #pragma unroll
  for (int j = 0; j < 8; ++j)
    #pragma unroll
    for (int i = 0; i < 4; ++i) acc[j][i] = 0.f;

  for (int k = 0; k < 128; k += 4){
    const float4 w0 = *(const float4*)&w2f[(k+0)*128 + c0];
    const float4 w1_ = *(const float4*)&w2f[(k+1)*128 + c0];
    const float4 w2_ = *(const float4*)&w2f[(k+2)*128 + c0];
    const float4 w3_ = *(const float4*)&w2f[(k+3)*128 + c0];
    #pragma unroll
    for (int j = 0; j < 8; ++j){
      const float4 a = *(const float4*)&sM[r0+j][k];
      acc[j][0] = fmaf(a.x,w0.x, fmaf(a.y,w1_.x, fmaf(a.z,w2_.x, fmaf(a.w,w3_.x, acc[j][0]))));
      acc[j][1] = fmaf(a.x,w0.y, fmaf(a.y,w1_.y, fmaf(a.z,w2_.y, fmaf(a.w,w3_.y, acc[j][1]))));
      acc[j][2] = fmaf(a.x,w0.z, fmaf(a.y,w1_.z, fmaf(a.z,w2_.z, fmaf(a.w,w3_.z, acc[j][2]))));
      acc[j][3] = fmaf(a.x,w0.w, fmaf(a.y,w1_.w, fmaf(a.z,w2_.w, fmaf(a.w,w3_.w, acc[j][3]))));
    }
  }

  // epilogue: bias, gate, f16 store (coalesced rows)
  float bb[4];
  #pragma unroll
  for (int i = 0; i < 4; ++i) bb[i] = b2[1 + c0 + i];
  #pragma unroll
  for (int j = 0; j < 8; ++j){
    const int r = r0 + j;
    const float kk = sK[r];
    half4 v;
    #pragma unroll
    for (int i = 0; i < 4; ++i) v[i] = (_Float16)((acc[j][i] + bb[i]) * kk);
    *(half4*)&ebuf[(size_t)(sl0 + r)*128 + c0] = v;
  }
}

// CSR gather: per node, sum cols 0..63, max cols 64..127 over its slot range in chunk.
__global__ __launch_bounds__(256) void gather_reduce(
    const _Float16* __restrict__ ebuf, const unsigned* __restrict__ starts,
    float* __restrict__ nfoc1, float* __restrict__ nfoc2,
    int c0, int c1, int first)
{
  const int t = threadIdx.x;
  const int n = blockIdx.x * 16 + (t >> 4);
  const int tg = t & 15;
  if (n >= NN) return;
  const int sb = (int)starts[n], se = (int)starts[n+1];
  int lo = sb > c0 ? sb : c0;
  int hi = se < c1 ? se : c1;
  const bool isSum = tg < 8;
  float* outp = isSum ? &nfoc1[(size_t)n*64 + tg*8] : &nfoc2[(size_t)n*64 + (tg-8)*8];
  float acc[8];
  if (first){
    const float init = isSum ? 0.f : -1e30f;
    #pragma unroll
    for (int k = 0; k < 8; ++k) acc[k] = init;
  } else {
    float4 a = *(const float4*)&outp[0];
    float4 b = *(const float4*)&outp[4];
    acc[0]=a.x; acc[1]=a.y; acc[2]=a.z; acc[3]=a.w;
    acc[4]=b.x; acc[5]=b.y; acc[6]=b.z; acc[7]=b.w;
  }
  for (int s = lo; s < hi; ++s){
    const half8 v = *(const half8*)&ebuf[(size_t)(s - c0)*128 + tg*8];
    if (isSum){
      #pragma unroll
      for (int k = 0; k < 8; ++k) acc[k] += (float)v[k];
    } else {
      #pragma unroll
      for (int k = 0; k < 8; ++k) acc[k] = fmaxf(acc[k], (float)v[k]);
    }
  }
  *(float4*)&outp[0] = make_float4(acc[0],acc[1],acc[2],acc[3]);
  *(float4*)&outp[4] = make_float4(acc[4],acc[5],acc[6],acc[7]);
}

// Node-side post: new_x = concat(x,nfoc1,nfoc2)@red_w+red_b; out += new_x@l2w+l2b
__global__ __launch_bounds__(256) void node_post(
    const float* __restrict__ x, const float* __restrict__ nfoc1,
    const float* __restrict__ nfoc2, const unsigned* __restrict__ counts,
    const float* __restrict__ redw, const float* __restrict__ redb,
    const float* __restrict__ l2w, const float* __restrict__ l2b,
    float* __restrict__ out)
{
  __shared__ float sC[64][197];
  __shared__ float sN[64][65];
  const int t = threadIdx.x;
  const int n0 = blockIdx.x * 64;
  const int rr = t >> 4, c4 = (t & 15) * 4;

  #pragma unroll
  for (int i = 0; i < 4; ++i){
    int r = rr + i*16, n = n0 + r;
    float4 xv = make_float4(0,0,0,0), f1 = make_float4(0,0,0,0), f2 = make_float4(0,0,0,0);
    bool has = false;
    if (n < NN){
      xv = *(const float4*)&x[(size_t)n*64 + c4];
      f1 = *(const float4*)&nfoc1[(size_t)n*64 + c4];
      f2 = *(const float4*)&nfoc2[(size_t)n*64 + c4];
      has = counts[n] > 0u;
    }
    sC[r][c4+0]=xv.x; sC[r][c4+1]=xv.y; sC[r][c4+2]=xv.z; sC[r][c4+3]=xv.w;
    sC[r][64+c4+0]=f1.x; sC[r][64+c4+1]=f1.y; sC[r][64+c4+2]=f1.z; sC[r][64+c4+3]=f1.w;
    sC[r][128+c4+0] = has ? f2.x : 0.f;
    sC[r][128+c4+1] = has ? f2.y : 0.f;
    sC[r][128+c4+2] = has ? f2.z : 0.f;
    sC[r][128+c4+3] = has ? f2.w : 0.f;
  }
  __syncthreads();

  const int c0 = (t & 15) * 4, r0 = (t >> 4) * 4;
  float acc[4][4];

  {
    const float4 b4 = *(const float4*)&redb[c0];
    #pragma unroll
    for (int j = 0; j < 4; ++j){ acc[j][0]=b4.x; acc[j][1]=b4.y; acc[j][2]=b4.z; acc[j][3]=b4.w; }
    #pragma unroll 4
    for (int k = 0; k < 192; ++k){
      const float4 w4 = *(const float4*)&redw[k*64 + c0];
      #pragma unroll
      for (int j = 0; j < 4; ++j){
        const float a = sC[r0+j][k];
        acc[j][0] = fmaf(a, w4.x, acc[j][0]);
        acc[j][1] = fmaf(a, w4.y, acc[j][1]);
        acc[j][2] = fmaf(a, w4.z, acc[j][2]);
        acc[j][3] = fmaf(a, w4.w, acc[j][3]);
      }
    }
    #pragma unroll
    for (int j = 0; j < 4; ++j)
      #pragma unroll
      for (int i = 0; i < 4; ++i) sN[r0+j][c0+i] = acc[j][i];
  }
  __syncthreads();

  gemm64(sN, l2w, l2b, t, acc);
  #pragma unroll
  for (int j = 0; j < 4; ++j){
    int n = n0 + r0 + j;
    if (n < NN){
      float4 cur = *(const float4*)&out[(size_t)n*64 + c0];
      cur.x += acc[j][0]; cur.y += acc[j][1]; cur.z += acc[j][2]; cur.w += acc[j][3];
      *(float4*)&out[(size_t)n*64 + c0] = cur;
    }
  }
}

extern "C" void kernel_launch(void* const* d_in, const int* in_sizes, int n_in,
                              void* d_out, int out_size, void* d_ws, size_t ws_size,
                              hipStream_t stream)
{
  const float* nf   = (const float*)d_in[0];
  const int*   src  = (const int*)d_in[1];
  const int*   dst  = (const int*)d_in[2];
  const float* rw1  = (const float*)d_in[3];
  const float* rb1  = (const float*)d_in[4];
  const float* rw2  = (const float*)d_in[5];
  const float* rb2  = (const float*)d_in[6];
  const float* l1w  = (const float*)d_in[7];
  const float* l1b  = (const float*)d_in[8];
  const float* l2w  = (const float*)d_in[9];
  const float* l2b  = (const float*)d_in[10];
  const float* mw1  = (const float*)d_in[11];
  const float* mb1  = (const float*)d_in[12];
  const float* mw2  = (const float*)d_in[13];
  const float* mb2  = (const float*)d_in[14];
  const float* redw = (const float*)d_in[15];
  const float* redb = (const float*)d_in[16];

  float* ws = (float*)d_ws;
  float*    x      = ws + XOFF;
  float*    P      = ws + POFF;
  float*    Q      = ws + QOFF;
  float*    nfoc1  = ws + N1OFF;
  float*    nfoc2  = ws + N2OFF;
  float*    w2f    = ws + W2FOFF;
  float*    w2g    = ws + W2GOFF;
  unsigned* counts = (unsigned*)(ws + CNTOFF);
  unsigned* starts = (unsigned*)(ws + STOFF);
  unsigned* cursor = (unsigned*)(ws + CUROFF);
  unsigned* perm   = (unsigned*)(ws + PERMOFF);
  _Float16* ebuf   = (_Float16*)(ws + EBUFOFF);
  float*    out    = (float*)d_out;

  hipLaunchKernelGGL(relayout_w2, dim3(260), dim3(256), 0, stream, mw2, w2f, w2g, counts);
  hipLaunchKernelGGL(node_pre, dim3(782), dim3(256), 0, stream,
                     nf, rw1, rb1, rw2, rb2, l1w, l1b, mw1, x, P, Q, out);
  hipLaunchKernelGGL(hist_k,   dim3(3125), dim3(256), 0, stream, dst, counts);
  hipLaunchKernelGGL(scan_k,   dim3(1),    dim3(1024), 0, stream, counts, starts, cursor);
  hipLaunchKernelGGL(assign_k, dim3(3125), dim3(256), 0, stream, dst, cursor, perm);

  // chunked edge phase: ebuf holds chunk_blocks*64 rows of 128 f16 (256B/row)
  const long total_blocks = NE / 64;                       // 12500
  long avail = (long)ws_size - (long)(EBUFOFF * 4);
  long chunk_blocks = avail / (64 * 256);
  if (chunk_blocks > total_blocks) chunk_blocks = total_blocks;
  if (chunk_blocks < 1) chunk_blocks = 1;

  for (long b0 = 0; b0 < total_blocks; b0 += chunk_blocks){
    long nb = total_blocks - b0;
    if (nb > chunk_blocks) nb = chunk_blocks;
    const int c0 = (int)(b0 * 64), c1 = (int)((b0 + nb) * 64);
    hipLaunchKernelGGL(edge_mlp2, dim3((unsigned)nb), dim3(256), 0, stream,
                       src, dst, P, Q, mb1, w2f, w2g, mb2, perm + c0, ebuf);
    hipLaunchKernelGGL(gather_reduce, dim3(3125), dim3(256), 0, stream,
                       ebuf, starts, nfoc1, nfoc2, c0, c1, (b0 == 0) ? 1 : 0);
  }

  hipLaunchKernelGGL(node_post, dim3(782), dim3(256), 0, stream,
                     x, nfoc1, nfoc2, counts, redw, redb, l2w, l2b, out);
}

// Round 4
// 546.617 us; speedup vs baseline: 2.5931x; 1.4284x over previous
//
#include <hip/hip_runtime.h>

#define NN 50000
#define NE 800000

typedef _Float16 half8 __attribute__((ext_vector_type(8)));
typedef _Float16 half4 __attribute__((ext_vector_type(4)));
typedef float f32x4 __attribute__((ext_vector_type(4)));

// ws layout (float offsets)
static const size_t XOFF   = 0;          // x      [50000*64] f32
static const size_t POFF   = 3200000;    // P      [50000*128] f16
static const size_t QOFF   = 6400000;    // Q      [50000*128] f16
static const size_t N1OFF  = 9600000;    // nfoc1  [50000*64] f32
static const size_t N2OFF  = 12800000;   // nfoc2  [50000*64] u32 (monotonic-encoded)
static const size_t W2TOFF = 16000000;   // w2t    [128 cols][128 k] f16 (col-major)
static const size_t W2GOFF = 16008192;   // w2gate [128] f32
static const size_t CNTOFF = 16008320;   // counts [50000] u32
static const size_t STOFF  = 16058320;   // starts [50001] u32
static const size_t CUROFF = 16108321;   // cursor [50000] u32
static const size_t PERMOFF= 16158321;   // perm   [800000] u32

__device__ __forceinline__ unsigned fenc(float f){
  unsigned b = __float_as_uint(f);
  return (b & 0x80000000u) ? ~b : (b | 0x80000000u);
}
__device__ __forceinline__ float fdec(unsigned u){
  return (u & 0x80000000u) ? __uint_as_float(u & 0x7fffffffu) : __uint_as_float(~u);
}
__device__ __forceinline__ float lrelu(float v){ return v > 0.f ? v : 0.2f * v; }

// 64x64 tile GEMM: acc[4][4] = bias + sIn(64x64, pad65) @ W(64x64 row-major)
__device__ __forceinline__ void gemm64(const float (*sIn)[65], const float* __restrict__ W,
                                       const float* __restrict__ bias, int t, float acc[4][4])
{
  const int c0 = (t & 15) * 4, r0 = (t >> 4) * 4;
  const float4 b4 = *(const float4*)&bias[c0];
  #pragma unroll
  for (int j = 0; j < 4; ++j){ acc[j][0]=b4.x; acc[j][1]=b4.y; acc[j][2]=b4.z; acc[j][3]=b4.w; }
  #pragma unroll 4
  for (int k = 0; k < 64; ++k){
    const float4 w4 = *(const float4*)&W[k*64 + c0];
    #pragma unroll
    for (int j = 0; j < 4; ++j){
      const float a = sIn[r0+j][k];
      acc[j][0] = fmaf(a, w4.x, acc[j][0]);
      acc[j][1] = fmaf(a, w4.y, acc[j][1]);
      acc[j][2] = fmaf(a, w4.z, acc[j][2]);
      acc[j][3] = fmaf(a, w4.w, acc[j][3]);
    }
  }
}

// msg_w2 [128][129] -> w2t f16 col-major [col][k] + w2gate f32[128]; zero counts.
__global__ __launch_bounds__(256) void relayout_w2(const float* __restrict__ w2,
                                                   _Float16* __restrict__ w2t,
                                                   float* __restrict__ w2g,
                                                   unsigned* __restrict__ counts)
{
  int i = blockIdx.x * 256 + threadIdx.x;
  if (i < 16384){
    int c = i >> 7, k = i & 127;
    w2t[i] = (_Float16)w2[k*129 + 1 + c];
  } else if (i < 16512){
    int k = i - 16384;
    w2g[k] = w2[k*129];
  } else if (i < 16512 + NN){
    counts[i - 16512] = 0u;
  }
}

// histogram of dst
__global__ __launch_bounds__(256) void hist_k(const int* __restrict__ dst,
                                              unsigned* __restrict__ counts)
{
  int e = blockIdx.x * 256 + threadIdx.x;
  if (e < NE) atomicAdd(&counts[dst[e]], 1u);
}

// single-block exclusive scan of counts -> starts[0..NN], cursor copy
__global__ __launch_bounds__(1024) void scan_k(const unsigned* __restrict__ counts,
                                               unsigned* __restrict__ starts,
                                               unsigned* __restrict__ cursor)
{
  __shared__ unsigned sc[1024];
  const int i = threadIdx.x;
  const int L = 49;               // 1024*49 = 50176 >= 50000
  const int base = i * L;
  unsigned s = 0;
  for (int j = 0; j < L; ++j){
    int n = base + j;
    if (n < NN) s += counts[n];
  }
  sc[i] = s; __syncthreads();
  for (int d = 1; d < 1024; d <<= 1){
    unsigned v = 0;
    if (i >= d) v = sc[i - d];
    __syncthreads();
    sc[i] += v;
    __syncthreads();
  }
  unsigned run = sc[i] - s;       // exclusive offset
  for (int j = 0; j < L; ++j){
    int n = base + j;
    if (n < NN){
      starts[n] = run; cursor[n] = run;
      run += counts[n];
    }
  }
  if (i == 1023) starts[NN] = sc[1023];
}

// slot assignment: perm[slot] = edge id, slots grouped by dst
__global__ __launch_bounds__(256) void assign_k(const int* __restrict__ dst,
                                                unsigned* __restrict__ cursor,
                                                unsigned* __restrict__ perm)
{
  int e = blockIdx.x * 256 + threadIdx.x;
  if (e < NE){
    unsigned slot = atomicAdd(&cursor[dst[e]], 1u);
    perm[slot] = (unsigned)e;
  }
}

// Node-side precompute: x = residual(nf); x1 = x@l1w+b -> out; P/Q = x@W1 halves (f16).
// Also zero-inits nfoc1 / nfoc2 for this node range.
__global__ __launch_bounds__(256) void node_pre(
    const float* __restrict__ nf,
    const float* __restrict__ rw1, const float* __restrict__ rb1,
    const float* __restrict__ rw2, const float* __restrict__ rb2,
    const float* __restrict__ l1w, const float* __restrict__ l1b,
    const float* __restrict__ w1,   // msg_w1 [128][128]
    float* __restrict__ x_out, _Float16* __restrict__ Pp, _Float16* __restrict__ Qp,
    float* __restrict__ out,
    float* __restrict__ nfoc1, unsigned* __restrict__ nfoc2)
{
  __shared__ float sA[64][65];
  __shared__ float sB[64][65];
  const int t = threadIdx.x;
  const int n0 = blockIdx.x * 64;
  const int rr = t >> 4, c4 = (t & 15) * 4;

  #pragma unroll
  for (int i = 0; i < 4; ++i){
    int r = rr + i*16, n = n0 + r;
    float4 v = make_float4(0.f,0.f,0.f,0.f);
    if (n < NN) v = *(const float4*)&nf[n*64 + c4];
    sA[r][c4+0]=v.x; sA[r][c4+1]=v.y; sA[r][c4+2]=v.z; sA[r][c4+3]=v.w;
  }
  __syncthreads();

  float acc[4][4];
  const int c0 = (t & 15) * 4, r0 = (t >> 4) * 4;

  gemm64(sA, rw1, rb1, t, acc);
  #pragma unroll
  for (int j = 0; j < 4; ++j)
    #pragma unroll
    for (int i = 0; i < 4; ++i) sB[r0+j][c0+i] = acc[j][i];
  __syncthreads();

  gemm64(sB, rw2, rb2, t, acc);
  #pragma unroll
  for (int j = 0; j < 4; ++j)
    #pragma unroll
    for (int i = 0; i < 4; ++i) acc[j][i] += sA[r0+j][c0+i];
  #pragma unroll
  for (int j = 0; j < 4; ++j){
    #pragma unroll
    for (int i = 0; i < 4; ++i) sA[r0+j][c0+i] = acc[j][i];
    int n = n0 + r0 + j;
    if (n < NN){
      float4 v = make_float4(acc[j][0],acc[j][1],acc[j][2],acc[j][3]);
      *(float4*)&x_out[n*64 + c0] = v;
    }
  }
  __syncthreads();

  gemm64(sA, l1w, l1b, t, acc);
  #pragma unroll
  for (int j = 0; j < 4; ++j){
    int n = n0 + r0 + j;
    if (n < NN){
      float4 v = make_float4(acc[j][0],acc[j][1],acc[j][2],acc[j][3]);
      *(float4*)&out[n*64 + c0] = v;
    }
  }

  #pragma unroll
  for (int part = 0; part < 2; ++part){
    _Float16* dstp = part ? Qp : Pp;
    const float* Wp = w1 + (size_t)part * 64 * 128;
    for (int ch = 0; ch < 2; ++ch){
      float a2[4][4];
      #pragma unroll
      for (int j = 0; j < 4; ++j)
        #pragma unroll
        for (int i = 0; i < 4; ++i) a2[j][i] = 0.f;
      #pragma unroll 4
      for (int k = 0; k < 64; ++k){
        const float4 w4 = *(const float4*)&Wp[k*128 + ch*64 + c0];
        #pragma unroll
        for (int j = 0; j < 4; ++j){
          const float a = sA[r0+j][k];
          a2[j][0] = fmaf(a, w4.x, a2[j][0]);
          a2[j][1] = fmaf(a, w4.y, a2[j][1]);
          a2[j][2] = fmaf(a, w4.z, a2[j][2]);
          a2[j][3] = fmaf(a, w4.w, a2[j][3]);
        }
      }
      #pragma unroll
      for (int j = 0; j < 4; ++j){
        int n = n0 + r0 + j;
        if (n < NN){
          half4 v;
          #pragma unroll
          for (int i = 0; i < 4; ++i) v[i] = (_Float16)a2[j][i];
          *(half4*)&dstp[(size_t)n*128 + ch*64 + c0] = v;
        }
      }
    }
  }

  // zero-init scatter targets for this node tile
  #pragma unroll
  for (int i = 0; i < 16; ++i){
    int idx = t + 256*i;                 // 0..4095
    size_t flat = (size_t)n0*64 + idx;
    if (flat < (size_t)NN*64){ nfoc1[flat] = 0.f; nfoc2[flat] = 0u; }
  }
}

// Edge MLP (MFMA) + fused segmented scatter-reduce. 64 dst-sorted edges per block.
__global__ __launch_bounds__(256) void edge_mlp3(
    const int* __restrict__ src, const int* __restrict__ dst,
    const _Float16* __restrict__ Pp, const _Float16* __restrict__ Qp,
    const float* __restrict__ b1,
    const _Float16* __restrict__ w2t, const float* __restrict__ w2g,
    const float* __restrict__ b2,
    const unsigned* __restrict__ perm,
    float* __restrict__ nfoc1, unsigned* __restrict__ nfoc2)
{
  __shared__ _Float16 sMh[64][136];   // mid, f16, padded stride (conflict-free frags)
  __shared__ float sOut[64][132];     // gated f32 outputs
  __shared__ float sK[64];
  __shared__ int   sD[64];
  __shared__ float sPart[64][4];
  const int t = threadIdx.x;
  const int lane = t & 63, wave = t >> 6;
  const int sl0 = blockIdx.x * 64;

  // phase 1: gather P[src]+Q[dst]+b1, leaky-relu -> sMh (f16). 4 threads/edge.
  {
    const int el = t >> 2, q = t & 3;
    const unsigned e = perm[sl0 + el];
    const int s = src[e], d = dst[e];
    if (q == 0) sD[el] = d;
    #pragma unroll
    for (int i = 0; i < 4; ++i){
      const int c = q*32 + i*8;
      const half8 ph = *(const half8*)&Pp[(size_t)s*128 + c];
      const half8 qh = *(const half8*)&Qp[(size_t)d*128 + c];
      float bb[8];
      *(float4*)&bb[0] = *(const float4*)&b1[c];
      *(float4*)&bb[4] = *(const float4*)&b1[c+4];
      half8 rv;
      #pragma unroll
      for (int j = 0; j < 8; ++j){
        float v = (float)ph[j] + (float)qh[j] + bb[j];
        rv[j] = (_Float16)lrelu(v);
      }
      *(half8*)&sMh[el][c] = rv;
    }
  }
  __syncthreads();

  // phase 2: gate = sigmoid(mid . w2g + b2[0]); wave w covers k in [32w,32w+32)
  {
    float a = 0.f;
    #pragma unroll
    for (int i = 0; i < 4; ++i){
      const half8 v = *(const half8*)&sMh[lane][wave*32 + i*8];
      #pragma unroll
      for (int j = 0; j < 8; ++j) a = fmaf((float)v[j], w2g[wave*32 + i*8 + j], a);
    }
    sPart[lane][wave] = a;
  }
  __syncthreads();
  if (t < 64){
    float g = sPart[t][0] + sPart[t][1] + sPart[t][2] + sPart[t][3] + b2[0];
    sK[t] = 1.f / (1.f + expf(-g));
  }
  __syncthreads();

  // phase 3: o = mid(64x128) @ w2(128x128) via MFMA 16x16x16 f16.
  // wave w owns col-tiles {2w, 2w+1}; loops row-tiles 0..3.
  {
    const int lane15 = lane & 15, kgrp = lane >> 4;
    const int ct0 = wave * 2;
    half4 bf[2][8];
    float bias_c[2];
    #pragma unroll
    for (int cc = 0; cc < 2; ++cc){
      const int col = (ct0 + cc)*16 + lane15;
      bias_c[cc] = b2[1 + col];
      const _Float16* wc = &w2t[(size_t)col*128 + kgrp*4];
      #pragma unroll
      for (int kb = 0; kb < 8; ++kb)
        bf[cc][kb] = *(const half4*)&wc[kb*16];
    }
    #pragma unroll
    for (int rt = 0; rt < 4; ++rt){
      const _Float16* ar = &sMh[rt*16 + lane15][kgrp*4];
      half4 af[8];
      #pragma unroll
      for (int kb = 0; kb < 8; ++kb) af[kb] = *(const half4*)&ar[kb*16];
      f32x4 a0 = {0.f,0.f,0.f,0.f}, a1 = {0.f,0.f,0.f,0.f};
      #pragma unroll
      for (int kb = 0; kb < 8; ++kb){
        a0 = __builtin_amdgcn_mfma_f32_16x16x16f16(af[kb], bf[0][kb], a0, 0, 0, 0);
        a1 = __builtin_amdgcn_mfma_f32_16x16x16f16(af[kb], bf[1][kb], a1, 0, 0, 0);
      }
      // epilogue: D[row][col], row = rt*16 + kgrp*4 + reg, col = ct*16 + lane15
      #pragma unroll
      for (int reg = 0; reg < 4; ++reg){
        const int row = rt*16 + kgrp*4 + reg;
        const float kk = sK[row];
        sOut[row][ ct0   *16 + lane15] = (a0[reg] + bias_c[0]) * kk;
        sOut[row][(ct0+1)*16 + lane15] = (a1[reg] + bias_c[1]) * kk;
      }
    }
  }
  __syncthreads();

  // phase 4: segmented reduce over dst-sorted rows; 2 threads/col x 32 rows each.
  {
    const int c = t & 127;
    const int rbeg = (t >> 7) * 32;
    const bool isSum = c < 64;
    float acc = isSum ? 0.f : -1e30f;
    int curd = sD[rbeg];
    for (int r = rbeg; r < rbeg + 32; ++r){
      const float v = sOut[r][c];
      acc = isSum ? (acc + v) : fmaxf(acc, v);
      const bool last = (r == rbeg + 31) || (sD[r + 1] != curd);
      if (last){
        if (isSum){
          unsafeAtomicAdd(&nfoc1[(size_t)curd*64 + c], acc);
          acc = 0.f;
        } else {
          atomicMax(&nfoc2[(size_t)curd*64 + (c - 64)], fenc(acc));
          acc = -1e30f;
        }
        if (r < rbeg + 31) curd = sD[r + 1];
      }
    }
  }
}

// Node-side post: new_x = concat(x,nfoc1,dec(nfoc2))@red_w+red_b; out += new_x@l2w+l2b
__global__ __launch_bounds__(256) void node_post(
    const float* __restrict__ x, const float* __restrict__ nfoc1,
    const unsigned* __restrict__ nfoc2, const unsigned* __restrict__ counts,
    const float* __restrict__ redw, const float* __restrict__ redb,
    const float* __restrict__ l2w, const float* __restrict__ l2b,
    float* __restrict__ out)
{
  __shared__ float sC[64][197];
  __shared__ float sN[64][65];
  const int t = threadIdx.x;
  const int n0 = blockIdx.x * 64;
  const int rr = t >> 4, c4 = (t & 15) * 4;

  #pragma unroll
  for (int i = 0; i < 4; ++i){
    int r = rr + i*16, n = n0 + r;
    float4 xv = make_float4(0,0,0,0), f1 = make_float4(0,0,0,0);
    uint4 f2 = make_uint4(0,0,0,0);
    bool has = false;
    if (n < NN){
      xv = *(const float4*)&x[(size_t)n*64 + c4];
      f1 = *(const float4*)&nfoc1[(size_t)n*64 + c4];
      f2 = *(const uint4*)&nfoc2[(size_t)n*64 + c4];
      has = counts[n] > 0u;
    }
    sC[r][c4+0]=xv.x; sC[r][c4+1]=xv.y; sC[r][c4+2]=xv.z; sC[r][c4+3]=xv.w;
    sC[r][64+c4+0]=f1.x; sC[r][64+c4+1]=f1.y; sC[r][64+c4+2]=f1.z; sC[r][64+c4+3]=f1.w;
    sC[r][128+c4+0] = has ? fdec(f2.x) : 0.f;
    sC[r][128+c4+1] = has ? fdec(f2.y) : 0.f;
    sC[r][128+c4+2] = has ? fdec(f2.z) : 0.f;
    sC[r][128+c4+3] = has ? fdec(f2.w) : 0.f;
  }
  __syncthreads();

  const int c0 = (t & 15) * 4, r0 = (t >> 4) * 4;
  float acc[4][4];

  {
    const float4 b4 = *(const float4*)&redb[c0];
    #pragma unroll
    for (int j = 0; j < 4; ++j){ acc[j][0]=b4.x; acc[j][1]=b4.y; acc[j][2]=b4.z; acc[j][3]=b4.w; }
    #pragma unroll 4
    for (int k = 0; k < 192; ++k){
      const float4 w4 = *(const float4*)&redw[k*64 + c0];
      #pragma unroll
      for (int j = 0; j < 4; ++j){
        const float a = sC[r0+j][k];
        acc[j][0] = fmaf(a, w4.x, acc[j][0]);
        acc[j][1] = fmaf(a, w4.y, acc[j][1]);
        acc[j][2] = fmaf(a, w4.z, acc[j][2]);
        acc[j][3] = fmaf(a, w4.w, acc[j][3]);
      }
    }
    #pragma unroll
    for (int j = 0; j < 4; ++j)
      #pragma unroll
      for (int i = 0; i < 4; ++i) sN[r0+j][c0+i] = acc[j][i];
  }
  __syncthreads();

  gemm64(sN, l2w, l2b, t, acc);
  #pragma unroll
  for (int j = 0; j < 4; ++j){
    int n = n0 + r0 + j;
    if (n < NN){
      float4 cur = *(const float4*)&out[(size_t)n*64 + c0];
      cur.x += acc[j][0]; cur.y += acc[j][1]; cur.z += acc[j][2]; cur.w += acc[j][3];
      *(float4*)&out[(size_t)n*64 + c0] = cur;
    }
  }
}

extern "C" void kernel_launch(void* const* d_in, const int* in_sizes, int n_in,
                              void* d_out, int out_size, void* d_ws, size_t ws_size,
                              hipStream_t stream)
{
  const float* nf   = (const float*)d_in[0];
  const int*   src  = (const int*)d_in[1];
  const int*   dst  = (const int*)d_in[2];
  const float* rw1  = (const float*)d_in[3];
  const float* rb1  = (const float*)d_in[4];
  const float* rw2  = (const float*)d_in[5];
  const float* rb2  = (const float*)d_in[6];
  const float* l1w  = (const float*)d_in[7];
  const float* l1b  = (const float*)d_in[8];
  const float* l2w  = (const float*)d_in[9];
  const float* l2b  = (const float*)d_in[10];
  const float* mw1  = (const float*)d_in[11];
  const float* mb1  = (const float*)d_in[12];
  const float* mw2  = (const float*)d_in[13];
  const float* mb2  = (const float*)d_in[14];
  const float* redw = (const float*)d_in[15];
  const float* redb = (const float*)d_in[16];

  float* ws = (float*)d_ws;
  float*     x      = ws + XOFF;
  _Float16*  P      = (_Float16*)(ws + POFF);
  _Float16*  Q      = (_Float16*)(ws + QOFF);
  float*     nfoc1  = ws + N1OFF;
  unsigned*  nfoc2  = (unsigned*)(ws + N2OFF);
  _Float16*  w2t    = (_Float16*)(ws + W2TOFF);
  float*     w2g    = ws + W2GOFF;
  unsigned*  counts = (unsigned*)(ws + CNTOFF);
  unsigned*  starts = (unsigned*)(ws + STOFF);
  unsigned*  cursor = (unsigned*)(ws + CUROFF);
  unsigned*  perm   = (unsigned*)(ws + PERMOFF);
  float*     out    = (float*)d_out;

  hipLaunchKernelGGL(relayout_w2, dim3(260), dim3(256), 0, stream, mw2, w2t, w2g, counts);
  hipLaunchKernelGGL(node_pre, dim3(782), dim3(256), 0, stream,
                     nf, rw1, rb1, rw2, rb2, l1w, l1b, mw1, x, P, Q, out, nfoc1, nfoc2);
  hipLaunchKernelGGL(hist_k,   dim3(3125), dim3(256), 0, stream, dst, counts);
  hipLaunchKernelGGL(scan_k,   dim3(1),    dim3(1024), 0, stream, counts, starts, cursor);
  hipLaunchKernelGGL(assign_k, dim3(3125), dim3(256), 0, stream, dst, cursor, perm);
  hipLaunchKernelGGL(edge_mlp3, dim3(12500), dim3(256), 0, stream,
                     src, dst, P, Q, mb1, w2t, w2g, mb2, perm, nfoc1, nfoc2);
  hipLaunchKernelGGL(node_post, dim3(782), dim3(256), 0, stream,
                     x, nfoc1, nfoc2, counts, redw, redb, l2w, l2b, out);
}

// Round 5
// 429.425 us; speedup vs baseline: 3.3008x; 1.2729x over previous
//
#include <hip/hip_runtime.h>

#define NN 50000
#define NE 800000

typedef _Float16 half8 __attribute__((ext_vector_type(8)));
typedef _Float16 half4 __attribute__((ext_vector_type(4)));
typedef float f32x4 __attribute__((ext_vector_type(4)));

// ws layout (float offsets)
static const size_t XOFF   = 0;          // x      [50000*64] f32
static const size_t POFF   = 3200000;    // P      [50000*128] f16
static const size_t QOFF   = 6400000;    // Q      [50000*128] f16
static const size_t N1OFF  = 9600000;    // nfoc1  [50000*64] f32
static const size_t N2OFF  = 12800000;   // nfoc2  [50000*64] u32 (monotonic-encoded)
static const size_t W2TOFF = 16000000;   // w2t    [128 cols][128 k] f16 (col-major)
static const size_t W2GOFF = 16008192;   // w2gate [128] f32
static const size_t CNTOFF = 16008320;   // counts [50000] u32
static const size_t CUROFF = 16058320;   // cursor [50000] u32
static const size_t PARTOFF= 16108320;   // partial[256] u32
static const size_t PERMOFF= 16108576;   // perm   [800000] u32

__device__ __forceinline__ unsigned fenc(float f){
  unsigned b = __float_as_uint(f);
  return (b & 0x80000000u) ? ~b : (b | 0x80000000u);
}
__device__ __forceinline__ float fdec(unsigned u){
  return (u & 0x80000000u) ? __uint_as_float(u & 0x7fffffffu) : __uint_as_float(~u);
}
__device__ __forceinline__ float lrelu(float v){ return v > 0.f ? v : 0.2f * v; }

// 64x64 tile GEMM: acc[4][4] = bias + sIn(64x64, pad65) @ W(64x64 row-major)
__device__ __forceinline__ void gemm64(const float (*sIn)[65], const float* __restrict__ W,
                                       const float* __restrict__ bias, int t, float acc[4][4])
{
  const int c0 = (t & 15) * 4, r0 = (t >> 4) * 4;
  const float4 b4 = *(const float4*)&bias[c0];
  #pragma unroll
  for (int j = 0; j < 4; ++j){ acc[j][0]=b4.x; acc[j][1]=b4.y; acc[j][2]=b4.z; acc[j][3]=b4.w; }
  #pragma unroll 4
  for (int k = 0; k < 64; ++k){
    const float4 w4 = *(const float4*)&W[k*64 + c0];
    #pragma unroll
    for (int j = 0; j < 4; ++j){
      const float a = sIn[r0+j][k];
      acc[j][0] = fmaf(a, w4.x, acc[j][0]);
      acc[j][1] = fmaf(a, w4.y, acc[j][1]);
      acc[j][2] = fmaf(a, w4.z, acc[j][2]);
      acc[j][3] = fmaf(a, w4.w, acc[j][3]);
    }
  }
}

// blocks 0..64: msg_w2 [128][129] -> w2t f16 col-major + w2gate f32.
// blocks 65+: histogram of dst (counts pre-zeroed by memset).
__global__ __launch_bounds__(256) void prep_k(const float* __restrict__ w2,
                                              _Float16* __restrict__ w2t,
                                              float* __restrict__ w2g,
                                              const int* __restrict__ dst,
                                              unsigned* __restrict__ counts)
{
  const int b = blockIdx.x;
  if (b < 65){
    int i = b * 256 + threadIdx.x;
    if (i < 16384){
      int c = i >> 7, k = i & 127;
      w2t[i] = (_Float16)w2[k*129 + 1 + c];
    } else if (i < 16512){
      int k = i - 16384;
      w2g[k] = w2[k*129];
    }
  } else {
    int e = (b - 65) * 256 + threadIdx.x;
    if (e < NE) atomicAdd(&counts[dst[e]], 1u);
  }
}

// per-block sums of counts -> partial[196]
__global__ __launch_bounds__(256) void scanA(const unsigned* __restrict__ counts,
                                             unsigned* __restrict__ partial)
{
  __shared__ unsigned s[256];
  const int t = threadIdx.x;
  const int idx = blockIdx.x * 256 + t;
  s[t] = (idx < NN) ? counts[idx] : 0u;
  __syncthreads();
  for (int d = 128; d > 0; d >>= 1){
    if (t < d) s[t] += s[t + d];
    __syncthreads();
  }
  if (t == 0) partial[blockIdx.x] = s[0];
}

// exclusive scan of partial[196] in place (256 padded)
__global__ __launch_bounds__(256) void scanB(unsigned* __restrict__ partial, int nb)
{
  __shared__ unsigned s[256];
  const int t = threadIdx.x;
  unsigned v = (t < nb) ? partial[t] : 0u;
  s[t] = v;
  __syncthreads();
  for (int d = 1; d < 256; d <<= 1){
    unsigned u = (t >= d) ? s[t - d] : 0u;
    __syncthreads();
    s[t] += u;
    __syncthreads();
  }
  if (t < nb) partial[t] = s[t] - v;   // exclusive
}

// block-local exclusive scan + global offset -> cursor
__global__ __launch_bounds__(256) void scanC(const unsigned* __restrict__ counts,
                                             const unsigned* __restrict__ partial,
                                             unsigned* __restrict__ cursor)
{
  __shared__ unsigned s[256];
  const int t = threadIdx.x;
  const int idx = blockIdx.x * 256 + t;
  unsigned v = (idx < NN) ? counts[idx] : 0u;
  s[t] = v;
  __syncthreads();
  for (int d = 1; d < 256; d <<= 1){
    unsigned u = (t >= d) ? s[t - d] : 0u;
    __syncthreads();
    s[t] += u;
    __syncthreads();
  }
  if (idx < NN) cursor[idx] = partial[blockIdx.x] + s[t] - v;
}

// slot assignment: perm[slot] = edge id, slots grouped by dst
__global__ __launch_bounds__(256) void assign_k(const int* __restrict__ dst,
                                                unsigned* __restrict__ cursor,
                                                unsigned* __restrict__ perm)
{
  int e = blockIdx.x * 256 + threadIdx.x;
  if (e < NE){
    unsigned slot = atomicAdd(&cursor[dst[e]], 1u);
    perm[slot] = (unsigned)e;
  }
}

// Node-side precompute: x = residual(nf); x1 = x@l1w+b -> out; P/Q = x@W1 halves (f16).
// Also zero-inits nfoc1 / nfoc2 for this node range.
__global__ __launch_bounds__(256) void node_pre(
    const float* __restrict__ nf,
    const float* __restrict__ rw1, const float* __restrict__ rb1,
    const float* __restrict__ rw2, const float* __restrict__ rb2,
    const float* __restrict__ l1w, const float* __restrict__ l1b,
    const float* __restrict__ w1,   // msg_w1 [128][128]
    float* __restrict__ x_out, _Float16* __restrict__ Pp, _Float16* __restrict__ Qp,
    float* __restrict__ out,
    float* __restrict__ nfoc1, unsigned* __restrict__ nfoc2)
{
  __shared__ float sA[64][65];
  __shared__ float sB[64][65];
  const int t = threadIdx.x;
  const int n0 = blockIdx.x * 64;
  const int rr = t >> 4, c4 = (t & 15) * 4;

  #pragma unroll
  for (int i = 0; i < 4; ++i){
    int r = rr + i*16, n = n0 + r;
    float4 v = make_float4(0.f,0.f,0.f,0.f);
    if (n < NN) v = *(const float4*)&nf[n*64 + c4];
    sA[r][c4+0]=v.x; sA[r][c4+1]=v.y; sA[r][c4+2]=v.z; sA[r][c4+3]=v.w;
  }
  __syncthreads();

  float acc[4][4];
  const int c0 = (t & 15) * 4, r0 = (t >> 4) * 4;

  gemm64(sA, rw1, rb1, t, acc);
  #pragma unroll
  for (int j = 0; j < 4; ++j)
    #pragma unroll
    for (int i = 0; i < 4; ++i) sB[r0+j][c0+i] = acc[j][i];
  __syncthreads();

  gemm64(sB, rw2, rb2, t, acc);
  #pragma unroll
  for (int j = 0; j < 4; ++j)
    #pragma unroll
    for (int i = 0; i < 4; ++i) acc[j][i] += sA[r0+j][c0+i];
  __syncthreads();
  #pragma unroll
  for (int j = 0; j < 4; ++j){
    #pragma unroll
    for (int i = 0; i < 4; ++i) sA[r0+j][c0+i] = acc[j][i];
    int n = n0 + r0 + j;
    if (n < NN){
      float4 v = make_float4(acc[j][0],acc[j][1],acc[j][2],acc[j][3]);
      *(float4*)&x_out[n*64 + c0] = v;
    }
  }
  __syncthreads();

  gemm64(sA, l1w, l1b, t, acc);
  #pragma unroll
  for (int j = 0; j < 4; ++j){
    int n = n0 + r0 + j;
    if (n < NN){
      float4 v = make_float4(acc[j][0],acc[j][1],acc[j][2],acc[j][3]);
      *(float4*)&out[n*64 + c0] = v;
    }
  }

  #pragma unroll
  for (int part = 0; part < 2; ++part){
    _Float16* dstp = part ? Qp : Pp;
    const float* Wp = w1 + (size_t)part * 64 * 128;
    for (int ch = 0; ch < 2; ++ch){
      float a2[4][4];
      #pragma unroll
      for (int j = 0; j < 4; ++j)
        #pragma unroll
        for (int i = 0; i < 4; ++i) a2[j][i] = 0.f;
      #pragma unroll 4
      for (int k = 0; k < 64; ++k){
        const float4 w4 = *(const float4*)&Wp[k*128 + ch*64 + c0];
        #pragma unroll
        for (int j = 0; j < 4; ++j){
          const float a = sA[r0+j][k];
          a2[j][0] = fmaf(a, w4.x, a2[j][0]);
          a2[j][1] = fmaf(a, w4.y, a2[j][1]);
          a2[j][2] = fmaf(a, w4.z, a2[j][2]);
          a2[j][3] = fmaf(a, w4.w, a2[j][3]);
        }
      }
      #pragma unroll
      for (int j = 0; j < 4; ++j){
        int n = n0 + r0 + j;
        if (n < NN){
          half4 v;
          #pragma unroll
          for (int i = 0; i < 4; ++i) v[i] = (_Float16)a2[j][i];
          *(half4*)&dstp[(size_t)n*128 + ch*64 + c0] = v;
        }
      }
    }
  }

  // zero-init scatter targets for this node tile
  #pragma unroll
  for (int i = 0; i < 16; ++i){
    int idx = t + 256*i;                 // 0..4095
    size_t flat = (size_t)n0*64 + idx;
    if (flat < (size_t)NN*64){ nfoc1[flat] = 0.f; nfoc2[flat] = 0u; }
  }
}

// Edge MLP (MFMA) + fused segmented scatter-reduce. 64 dst-sorted edges per block.
// 2 barriers; f16 staging both directions; gate fused into gather + applied in reduce.
__global__ __launch_bounds__(256) void edge_mlp4(
    const int* __restrict__ src, const int* __restrict__ dst,
    const _Float16* __restrict__ Pp, const _Float16* __restrict__ Qp,
    const float* __restrict__ b1,
    const _Float16* __restrict__ w2t, const float* __restrict__ w2g,
    const float* __restrict__ b2,
    const unsigned* __restrict__ perm,
    float* __restrict__ nfoc1, unsigned* __restrict__ nfoc2)
{
  __shared__ _Float16 sMh[64][136];    // mid (f16), padded stride
  __shared__ _Float16 sOutH[64][136];  // raw o+bias (f16), gate applied in phase 4
  __shared__ float sK[64];
  __shared__ int   sD[64];
  __shared__ float sPart[64][4];
  const int t = threadIdx.x;
  const int lane = t & 63, wave = t >> 6;
  const int sl0 = blockIdx.x * 64;

  // phase 1: gather P[src]+Q[dst]+b1, lrelu -> sMh; gate partial fused in.
  {
    const int el = t >> 2, q = t & 3;
    const unsigned e = perm[sl0 + el];
    const int s = src[e], d = dst[e];
    if (q == 0) sD[el] = d;
    float gp = 0.f;
    #pragma unroll
    for (int i = 0; i < 4; ++i){
      const int c = q*32 + i*8;
      const half8 ph = *(const half8*)&Pp[(size_t)s*128 + c];
      const half8 qh = *(const half8*)&Qp[(size_t)d*128 + c];
      float bb[8];
      *(float4*)&bb[0] = *(const float4*)&b1[c];
      *(float4*)&bb[4] = *(const float4*)&b1[c+4];
      half8 rv;
      #pragma unroll
      for (int j = 0; j < 8; ++j){
        float v = lrelu((float)ph[j] + (float)qh[j] + bb[j]);
        rv[j] = (_Float16)v;
        gp = fmaf(v, w2g[c + j], gp);
      }
      *(half8*)&sMh[el][c] = rv;
    }
    sPart[el][q] = gp;
  }
  __syncthreads();

  // sK (first 64 threads); MFMA below doesn't read sK, so no extra barrier.
  if (t < 64){
    float g = sPart[t][0] + sPart[t][1] + sPart[t][2] + sPart[t][3] + b2[0];
    sK[t] = 1.f / (1.f + expf(-g));
  }

  // phase 3: o = mid(64x128) @ w2(128x128) via MFMA 16x16x16 f16; store raw+bias f16.
  {
    const int lane15 = lane & 15, kgrp = lane >> 4;
    const int ct0 = wave * 2;
    half4 bf[2][8];
    float bias_c[2];
    #pragma unroll
    for (int cc = 0; cc < 2; ++cc){
      const int col = (ct0 + cc)*16 + lane15;
      bias_c[cc] = b2[1 + col];
      const _Float16* wc = &w2t[(size_t)col*128 + kgrp*4];
      #pragma unroll
      for (int kb = 0; kb < 8; ++kb)
        bf[cc][kb] = *(const half4*)&wc[kb*16];
    }
    #pragma unroll
    for (int rt = 0; rt < 4; ++rt){
      const _Float16* ar = &sMh[rt*16 + lane15][kgrp*4];
      half4 af[8];
      #pragma unroll
      for (int kb = 0; kb < 8; ++kb) af[kb] = *(const half4*)&ar[kb*16];
      f32x4 a0 = {0.f,0.f,0.f,0.f}, a1 = {0.f,0.f,0.f,0.f};
      #pragma unroll
      for (int kb = 0; kb < 8; ++kb){
        a0 = __builtin_amdgcn_mfma_f32_16x16x16f16(af[kb], bf[0][kb], a0, 0, 0, 0);
        a1 = __builtin_amdgcn_mfma_f32_16x16x16f16(af[kb], bf[1][kb], a1, 0, 0, 0);
      }
      #pragma unroll
      for (int reg = 0; reg < 4; ++reg){
        const int row = rt*16 + kgrp*4 + reg;
        sOutH[row][ ct0   *16 + lane15] = (_Float16)(a0[reg] + bias_c[0]);
        sOutH[row][(ct0+1)*16 + lane15] = (_Float16)(a1[reg] + bias_c[1]);
      }
    }
  }
  __syncthreads();

  // phase 4: segmented reduce (gate applied here); 2 threads/col x 32 rows each.
  {
    const int c = t & 127;
    const int rbeg = (t >> 7) * 32;
    const bool isSum = c < 64;
    float acc = isSum ? 0.f : -1e30f;
    int curd = sD[rbeg];
    for (int r = rbeg; r < rbeg + 32; ++r){
      const float v = (float)sOutH[r][c] * sK[r];
      acc = isSum ? (acc + v) : fmaxf(acc, v);
      const bool last = (r == rbeg + 31) || (sD[r + 1] != curd);
      if (last){
        if (isSum){
          unsafeAtomicAdd(&nfoc1[(size_t)curd*64 + c], acc);
          acc = 0.f;
        } else {
          atomicMax(&nfoc2[(size_t)curd*64 + (c - 64)], fenc(acc));
          acc = -1e30f;
        }
        if (r < rbeg + 31) curd = sD[r + 1];
      }
    }
  }
}

// Node-side post: new_x = concat(x,nfoc1,dec(nfoc2))@red_w+red_b; out += new_x@l2w+l2b
__global__ __launch_bounds__(256) void node_post(
    const float* __restrict__ x, const float* __restrict__ nfoc1,
    const unsigned* __restrict__ nfoc2, const unsigned* __restrict__ counts,
    const float* __restrict__ redw, const float* __restrict__ redb,
    const float* __restrict__ l2w, const float* __restrict__ l2b,
    float* __restrict__ out)
{
  __shared__ float sC[64][197];
  __shared__ float sN[64][65];
  const int t = threadIdx.x;
  const int n0 = blockIdx.x * 64;
  const int rr = t >> 4, c4 = (t & 15) * 4;

  #pragma unroll
  for (int i = 0; i < 4; ++i){
    int r = rr + i*16, n = n0 + r;
    float4 xv = make_float4(0,0,0,0), f1 = make_float4(0,0,0,0);
    uint4 f2 = make_uint4(0,0,0,0);
    bool has = false;
    if (n < NN){
      xv = *(const float4*)&x[(size_t)n*64 + c4];
      f1 = *(const float4*)&nfoc1[(size_t)n*64 + c4];
      f2 = *(const uint4*)&nfoc2[(size_t)n*64 + c4];
      has = counts[n] > 0u;
    }
    sC[r][c4+0]=xv.x; sC[r][c4+1]=xv.y; sC[r][c4+2]=xv.z; sC[r][c4+3]=xv.w;
    sC[r][64+c4+0]=f1.x; sC[r][64+c4+1]=f1.y; sC[r][64+c4+2]=f1.z; sC[r][64+c4+3]=f1.w;
    sC[r][128+c4+0] = has ? fdec(f2.x) : 0.f;
    sC[r][128+c4+1] = has ? fdec(f2.y) : 0.f;
    sC[r][128+c4+2] = has ? fdec(f2.z) : 0.f;
    sC[r][128+c4+3] = has ? fdec(f2.w) : 0.f;
  }
  __syncthreads();

  const int c0 = (t & 15) * 4, r0 = (t >> 4) * 4;
  float acc[4][4];

  {
    const float4 b4 = *(const float4*)&redb[c0];
    #pragma unroll
    for (int j = 0; j < 4; ++j){ acc[j][0]=b4.x; acc[j][1]=b4.y; acc[j][2]=b4.z; acc[j][3]=b4.w; }
    #pragma unroll 4
    for (int k = 0; k < 192; ++k){
      const float4 w4 = *(const float4*)&redw[k*64 + c0];
      #pragma unroll
      for (int j = 0; j < 4; ++j){
        const float a = sC[r0+j][k];
        acc[j][0] = fmaf(a, w4.x, acc[j][0]);
        acc[j][1] = fmaf(a, w4.y, acc[j][1]);
        acc[j][2] = fmaf(a, w4.z, acc[j][2]);
        acc[j][3] = fmaf(a, w4.w, acc[j][3]);
      }
    }
    #pragma unroll
    for (int j = 0; j < 4; ++j)
      #pragma unroll
      for (int i = 0; i < 4; ++i) sN[r0+j][c0+i] = acc[j][i];
  }
  __syncthreads();

  gemm64(sN, l2w, l2b, t, acc);
  #pragma unroll
  for (int j = 0; j < 4; ++j){
    int n = n0 + r0 + j;
    if (n < NN){
      float4 cur = *(const float4*)&out[(size_t)n*64 + c0];
      cur.x += acc[j][0]; cur.y += acc[j][1]; cur.z += acc[j][2]; cur.w += acc[j][3];
      *(float4*)&out[(size_t)n*64 + c0] = cur;
    }
  }
}

extern "C" void kernel_launch(void* const* d_in, const int* in_sizes, int n_in,
                              void* d_out, int out_size, void* d_ws, size_t ws_size,
                              hipStream_t stream)
{
  const float* nf   = (const float*)d_in[0];
  const int*   src  = (const int*)d_in[1];
  const int*   dst  = (const int*)d_in[2];
  const float* rw1  = (const float*)d_in[3];
  const float* rb1  = (const float*)d_in[4];
  const float* rw2  = (const float*)d_in[5];
  const float* rb2  = (const float*)d_in[6];
  const float* l1w  = (const float*)d_in[7];
  const float* l1b  = (const float*)d_in[8];
  const float* l2w  = (const float*)d_in[9];
  const float* l2b  = (const float*)d_in[10];
  const float* mw1  = (const float*)d_in[11];
  const float* mb1  = (const float*)d_in[12];
  const float* mw2  = (const float*)d_in[13];
  const float* mb2  = (const float*)d_in[14];
  const float* redw = (const float*)d_in[15];
  const float* redb = (const float*)d_in[16];

  float* ws = (float*)d_ws;
  float*     x      = ws + XOFF;
  _Float16*  P      = (_Float16*)(ws + POFF);
  _Float16*  Q      = (_Float16*)(ws + QOFF);
  float*     nfoc1  = ws + N1OFF;
  unsigned*  nfoc2  = (unsigned*)(ws + N2OFF);
  _Float16*  w2t    = (_Float16*)(ws + W2TOFF);
  float*     w2g    = ws + W2GOFF;
  unsigned*  counts = (unsigned*)(ws + CNTOFF);
  unsigned*  cursor = (unsigned*)(ws + CUROFF);
  unsigned*  partial= (unsigned*)(ws + PARTOFF);
  unsigned*  perm   = (unsigned*)(ws + PERMOFF);
  float*     out    = (float*)d_out;

  hipMemsetAsync(counts, 0, NN * sizeof(unsigned), stream);
  hipLaunchKernelGGL(prep_k, dim3(65 + 3125), dim3(256), 0, stream, mw2, w2t, w2g, dst, counts);
  hipLaunchKernelGGL(scanA, dim3(196), dim3(256), 0, stream, counts, partial);
  hipLaunchKernelGGL(scanB, dim3(1),   dim3(256), 0, stream, partial, 196);
  hipLaunchKernelGGL(scanC, dim3(196), dim3(256), 0, stream, counts, partial, cursor);
  hipLaunchKernelGGL(assign_k, dim3(3125), dim3(256), 0, stream, dst, cursor, perm);
  hipLaunchKernelGGL(node_pre, dim3(782), dim3(256), 0, stream,
                     nf, rw1, rb1, rw2, rb2, l1w, l1b, mw1, x, P, Q, out, nfoc1, nfoc2);
  hipLaunchKernelGGL(edge_mlp4, dim3(12500), dim3(256), 0, stream,
                     src, dst, P, Q, mb1, w2t, w2g, mb2, perm, nfoc1, nfoc2);
  hipLaunchKernelGGL(node_post, dim3(782), dim3(256), 0, stream,
                     x, nfoc1, nfoc2, counts, redw, redb, l2w, l2b, out);
}